// Round 5
// baseline (359.362 us; speedup 1.0000x reference)
//
#include <hip/hip_runtime.h>
#include <hip/hip_bf16.h>
#include <math.h>

// ---------- types ----------
typedef __attribute__((ext_vector_type(8))) __bf16 bf16x8;
typedef __attribute__((ext_vector_type(4))) float f32x4;

// fp32 -> bf16 round-to-nearest-even
__device__ __forceinline__ unsigned short f2bf(float f) {
    union { float f; unsigned u; } v; v.f = f;
    unsigned r = v.u + 0x7fffu + ((v.u >> 16) & 1u);
    return (unsigned short)(r >> 16);
}
// pack two fp32 into one dword of two bf16 (lo, hi)
__device__ __forceinline__ unsigned int pk(float a, float b) {
    union { float f; unsigned u; } x, y; x.f = a; y.f = b;
    unsigned ra = (x.u + 0x7fffu + ((x.u >> 16) & 1u)) >> 16;
    unsigned rb = (y.u + 0x7fffu + ((y.u >> 16) & 1u)) & 0xffff0000u;
    return ra | rb;
}

// async global->LDS, 16 B per lane; LDS dest = wave-uniform base + lane*16
__device__ __forceinline__ void gl2lds16(const unsigned short* g, unsigned short* l) {
    __builtin_amdgcn_global_load_lds(
        (const __attribute__((address_space(1))) unsigned int*)(g),
        (__attribute__((address_space(3))) unsigned int*)(l), 16, 0, 0);
}

// ---------- setup kernel ----------
// block 0: packed membership table tbl[f] = used | (lslot+1)<<8
// blocks 1..448: weight transpose+convert, 64x64 LDS tiles
struct SetupArgs {
    const int *and_pairs, *or_pairs, *not_idx, *lidx;
    int* tbl;                       // 64 ints
    const float* W[5];
    unsigned short* WT[5];
    int K[5], N[5];
    int tstart[6];
};

__global__ __launch_bounds__(256) void setup_kernel(SetupArgs a) {
    __shared__ float tile[64][65];
    const int blk = blockIdx.x;
    const int tid = threadIdx.x;

    if (blk == 0) {
        if (tid < 64) {
            const int f = tid;
            int u = 0;
            for (int i = 0; i < 32; i++) u |= (a.and_pairs[i] == f);
            for (int i = 0; i < 16; i++) u |= (a.or_pairs[i] == f);
            int isnot = 0;
            for (int i = 0; i < 8; i++)  isnot |= (a.not_idx[i] == f);
            int ls = -1;
            for (int l = 0; l < 16; l++) if (a.lidx[l] == f) ls = l;
            if (isnot) ls = -1;          // tanh epilogue writes these slots
            a.tbl[f] = (u | isnot) | ((ls + 1) << 8);
        }
        return;
    }

    const int bx = blk - 1;
    int m = 0;
    while (bx >= a.tstart[m + 1]) m++;
    const float* src = a.W[m];
    unsigned short* dst = a.WT[m];
    const int K = a.K[m], N = a.N[m];
    const int t = bx - a.tstart[m];
    const int ntn = N >> 6;
    const int tk = t / ntn, tn = t % ntn;
    const int c = tid & 63, r0 = tid >> 6;
    #pragma unroll
    for (int r = r0; r < 64; r += 4)
        tile[r][c] = src[(size_t)(tk * 64 + r) * N + tn * 64 + c];
    __syncthreads();
    #pragma unroll
    for (int r = r0; r < 64; r += 4)
        dst[(size_t)(tn * 64 + r) * K + tk * 64 + c] = f2bf(tile[c][r]);
}

// ---------- prep kernel: pure streaming, no LDS, no syncs ----------
struct PrepArgs {
    const float* fv;
    unsigned short* fvb;
    const int* tbl;
    float* out;
};

__global__ __launch_bounds__(256) void prep_kernel(PrepArgs a) {
    const int t = blockIdx.x * 256 + threadIdx.x;   // 8 consecutive floats
    const size_t e = (size_t)t * 8;
    const int c = (int)(e & 511);
    const int f = (int)((e >> 9) & 63);
    const int b = (int)(e >> 15);
    const float4 v0 = *(const float4*)(a.fv + e);
    const float4 v1 = *(const float4*)(a.fv + e + 4);
    const int tb = a.tbl[f];                        // wave-uniform
    const int u  = tb & 0xff;
    const int ls = (tb >> 8) - 1;
    if (u) {
        uint4 o;
        o.x = pk(v0.x, v0.y); o.y = pk(v0.z, v0.w);
        o.z = pk(v1.x, v1.y); o.w = pk(v1.z, v1.w);
        ((uint4*)a.fvb)[t] = o;
    }
    if (ls >= 0) {
        float* d = a.out + ((size_t)b * 40 + 24 + ls) * 512 + c;
        *(float4*)(d)     = v0;
        *(float4*)(d + 4) = v1;
    }
}

// ---------- fused two-layer GEMM segment ----------
// Block computes BM=64 rows x ALL 512 cols, so the L2 stage's A (=hid) is
// exactly this block's L1 output -> full MLP fused, hid lives in LDS only.
// 4 waves; wave w owns cols [w*128, +128): acc[4][8] (64x128 per wave).
// A: global_load_lds staged, 2-buf, XOR-swizzled chunks (as before).
// B (W1T/W2T): per-lane direct global->reg 16B fragment loads; the weight
// tiles are 0.5-1 MB and L2-resident, re-read by every block (no LDS, no
// extra barriers). Fragment = WT[n][k-chunk], n = wn+ni*16+(lane&15),
// k-chunk = (lane>>4)*8 -- same per-lane layout the LDS path produced.
// hid LDS [64][512] bf16, 16B-chunk XOR swizzle: byte = r*1024 +
// ((c8 ^ (r&7))*16) + (col&7)*2 -> L2-stage ds_read_b128 is 2-way max.
// PATH 0: relu->hid(LDS)->L2->out fp32 (+bias), rows m=b*P+p, q=QBASE+p
// PATH 2: single layer, tanh->out, rows m=b*8+i, q=qmap[i]
// SRCM 0: A row m = concat(fvb[b,idx[2p]], fvb[b,idx[2p+1]]), K1=1024
// SRCM 1: A row m = fvb[b, idx[i]], K1=512
#define LOADB(DST, WTP, KD, K0)                                              \
    _Pragma("unroll") for (int ni = 0; ni < 8; ni++)                         \
        DST[ni] = *(const bf16x8*)((WTP) +                                   \
            (size_t)(wn + ni * 16 + ln15) * (KD) + (K0) + kq * 8);

#define MMAC(BF, AF)                                                         \
    _Pragma("unroll") for (int mi = 0; mi < 4; mi++)                         \
    _Pragma("unroll") for (int ni = 0; ni < 8; ni++)                         \
        acc[mi][ni] = __builtin_amdgcn_mfma_f32_16x16x32_bf16(               \
            AF[mi], BF[ni], acc[mi][ni], 0, 0, 0);

template <int P, int K1, int SRCM, int PATH, int QBASE>
__device__ __forceinline__ void fused_seg(
    const unsigned short* __restrict__ A,
    const int* __restrict__ idx,
    const unsigned short* __restrict__ W1T,
    const float* __restrict__ b1,
    const unsigned short* __restrict__ W2T,
    const float* __restrict__ b2,
    float* __restrict__ out,
    const int* __restrict__ leftover,
    int local,
    unsigned short* As, unsigned short* hid) {

    const int tid  = threadIdx.x;
    const int lane = tid & 63, w = tid >> 6;
    const int ln15 = lane & 15;
    const int kq   = lane >> 4;          // k-chunk quad 0..3
    const int wn   = w * 128;            // wave's col base
    const int m0   = local * 64;         // block's row base

    // --- A staging: wave w stages rows [w*16, +16); lane l -> row l>>2,
    // swizzled source k-chunk ((l&3)^((l>>2)&3))*8 shorts (16 B)
    const int skin = ((lane & 3) ^ ((lane >> 2) & 3)) * 8;
    const unsigned short *ar0, *ar1;
    {
        const int m = m0 + w * 16 + (lane >> 2);
        if constexpr (SRCM == 0) {
            const int b = m / P, p = m % P;
            ar0 = A + ((size_t)b * 64 + idx[2 * p]) * 512;
            ar1 = A + ((size_t)b * 64 + idx[2 * p + 1]) * 512;
        } else {
            const int b = m >> 3, i = m & 7;
            ar0 = A + ((size_t)b * 64 + idx[i]) * 512;
            ar1 = ar0;
        }
    }
    auto stageA = [&](int buf, int t) {
        const int k0 = t * 32;
        const unsigned short* src;
        if constexpr (SRCM == 0)
            src = (k0 >= 512 ? ar1 + (k0 - 512) : ar0 + k0) + skin;
        else
            src = ar0 + k0 + skin;
        gl2lds16(src, &As[buf * 2048 + w * 512]);
    };
    const int xsel = (kq ^ (lane & 3)) * 8;   // frag-read chunk slot

    f32x4 acc[4][8];
    #pragma unroll
    for (int mi = 0; mi < 4; mi++)
        #pragma unroll
        for (int ni = 0; ni < 8; ni++)
            acc[mi][ni] = f32x4{0.f, 0.f, 0.f, 0.f};

    bf16x8 bA[8], bB[8];

    // ---- L1: acc = A[64,K1] @ W1[K1,512] ----
    constexpr int NT1 = K1 / 32;   // even
    stageA(0, 0);
    LOADB(bA, W1T, K1, 0);
    __syncthreads();
    for (int t = 0; t < NT1; t += 2) {
        // even step: A buf0, B = bA; prefetch buf1 / bB
        stageA(1, t + 1);
        bf16x8 af[4];
        #pragma unroll
        for (int mi = 0; mi < 4; mi++)
            af[mi] = *(const bf16x8*)&As[(mi * 16 + ln15) * 32 + xsel];
        LOADB(bB, W1T, K1, (t + 1) * 32);
        MMAC(bA, af);
        __syncthreads();
        // odd step: A buf1, B = bB; prefetch buf0 / bA
        if (t + 2 < NT1) stageA(0, t + 2);
        #pragma unroll
        for (int mi = 0; mi < 4; mi++)
            af[mi] = *(const bf16x8*)&As[2048 + (mi * 16 + ln15) * 32 + xsel];
        if (t + 2 < NT1) { LOADB(bA, W1T, K1, (t + 2) * 32); }
        MMAC(bB, af);
        __syncthreads();
    }

    if constexpr (PATH == 2) {
        // single layer: tanh -> out at leftover slot
        int qmap[8];
        #pragma unroll
        for (int i = 0; i < 8; i++) {
            const int f = idx[i];
            int q = 24;
            for (int l = 0; l < 16; l++)
                if (leftover[l] == f) q = 24 + l;
            qmap[i] = q;
        }
        #pragma unroll
        for (int ni = 0; ni < 8; ni++) {
            const int n = wn + ni * 16 + ln15;
            const float bv = b1[n];
            #pragma unroll
            for (int mi = 0; mi < 4; mi++)
                #pragma unroll
                for (int j = 0; j < 4; j++) {
                    const int r = mi * 16 + kq * 4 + j;
                    const int m = m0 + r;
                    const int b = m >> 3, i = m & 7;
                    out[((size_t)b * 40 + qmap[i]) * 512 + n] =
                        tanhf(acc[mi][ni][j] + bv);
                }
        }
        return;
    }

    // ---- L1 epilogue: relu -> bf16 -> hid LDS (XOR-swizzled chunks) ----
    #pragma unroll
    for (int ni = 0; ni < 8; ni++) {
        const int n  = wn + ni * 16 + ln15;
        const float bv = b1[n];
        const int c8 = n >> 3;
        const int cl = (n & 7) * 2;
        #pragma unroll
        for (int mi = 0; mi < 4; mi++)
            #pragma unroll
            for (int j = 0; j < 4; j++) {
                const int r = mi * 16 + kq * 4 + j;
                float v = acc[mi][ni][j] + bv;
                v = v > 0.f ? v : 0.f;
                *(unsigned short*)((char*)hid + r * 1024 +
                                   ((c8 ^ (r & 7)) * 16) + cl) = f2bf(v);
            }
    }
    #pragma unroll
    for (int mi = 0; mi < 4; mi++)
        #pragma unroll
        for (int ni = 0; ni < 8; ni++)
            acc[mi][ni] = f32x4{0.f, 0.f, 0.f, 0.f};
    LOADB(bA, W2T, 512, 0);
    __syncthreads();                       // hid visible; bA landed (vmcnt drain)

    // ---- L2: acc = hid[64,512] @ W2[512,512], A from LDS, no barriers ----
    for (int t2 = 0; t2 < 16; t2 += 2) {
        bf16x8 af[4];
        #pragma unroll
        for (int mi = 0; mi < 4; mi++) {
            const int r = mi * 16 + ln15;
            const int c8 = t2 * 4 + kq;
            af[mi] = *(const bf16x8*)((char*)hid + r * 1024 +
                                      ((c8 ^ (r & 7)) * 16));
        }
        LOADB(bB, W2T, 512, (t2 + 1) * 32);
        MMAC(bA, af);
        #pragma unroll
        for (int mi = 0; mi < 4; mi++) {
            const int r = mi * 16 + ln15;
            const int c8 = (t2 + 1) * 4 + kq;
            af[mi] = *(const bf16x8*)((char*)hid + r * 1024 +
                                      ((c8 ^ (r & 7)) * 16));
        }
        if (t2 + 2 < 16) { LOADB(bA, W2T, 512, (t2 + 2) * 32); }
        MMAC(bB, af);
    }

    // ---- L2 epilogue: +bias -> fp32 out ----
    #pragma unroll
    for (int ni = 0; ni < 8; ni++) {
        const int n  = wn + ni * 16 + ln15;
        const float bv = b2[n];
        #pragma unroll
        for (int mi = 0; mi < 4; mi++)
            #pragma unroll
            for (int j = 0; j < 4; j++) {
                const int r = mi * 16 + kq * 4 + j;
                const int m = m0 + r;
                const int b = m / P, p = m % P;    // P constexpr -> shifts
                out[((size_t)b * 40 + QBASE + p) * 512 + n] =
                    acc[mi][ni][j] + bv;
            }
    }
}

// ---------- fused phase kernel ----------
struct FArgs {
    const unsigned short *fvb, *and_W1T, *and_W2T, *or_W1T, *or_W2T, *not_WT;
    const int *and_pairs, *or_pairs, *not_idx, *leftover;
    const float *and_b1, *and_b2, *or_b1, *or_b2, *not_b;
    float* out;
};

__global__ __launch_bounds__(256, 2) void fused_phase(FArgs a) {
    __shared__ __align__(16) unsigned short As[2 * 64 * 32];   // 8 KB
    __shared__ __align__(16) unsigned short hid[64 * 512];     // 64 KB
    const int blk = blockIdx.x;
    if (blk < 256)        // and: M=16384 -> 256 blocks of 64 rows
        fused_seg<16, 1024, 0, 0, 0>(a.fvb, a.and_pairs, a.and_W1T, a.and_b1,
                                     a.and_W2T, a.and_b2, a.out, nullptr,
                                     blk, As, hid);
    else if (blk < 384)   // or: M=8192 -> 128 blocks
        fused_seg<8, 1024, 0, 0, 16>(a.fvb, a.or_pairs, a.or_W1T, a.or_b1,
                                     a.or_W2T, a.or_b2, a.out, nullptr,
                                     blk - 256, As, hid);
    else                  // not: M=8192, single layer tanh -> 128 blocks
        fused_seg<8, 512, 1, 2, 24>(a.fvb, a.not_idx, a.not_WT, a.not_b,
                                    nullptr, nullptr, a.out, a.leftover,
                                    blk - 384, As, hid);
}

// ---------- launch ----------
extern "C" void kernel_launch(void* const* d_in, const int* in_sizes, int n_in,
                              void* d_out, int out_size, void* d_ws, size_t ws_size,
                              hipStream_t stream) {
    const float* fv       = (const float*)d_in[0];
    const float* and_W1   = (const float*)d_in[1];
    const float* and_b1   = (const float*)d_in[2];
    const float* and_W2   = (const float*)d_in[3];
    const float* and_b2   = (const float*)d_in[4];
    const float* or_W1    = (const float*)d_in[5];
    const float* or_b1    = (const float*)d_in[6];
    const float* or_W2    = (const float*)d_in[7];
    const float* or_b2    = (const float*)d_in[8];
    const float* not_W    = (const float*)d_in[9];
    const float* not_b    = (const float*)d_in[10];
    const int* not_idx    = (const int*)d_in[11];
    const int* and_pairs  = (const int*)d_in[12];
    const int* or_pairs   = (const int*)d_in[13];
    const int* leftover   = (const int*)d_in[14];
    float* out = (float*)d_out;
    char* ws = (char*)d_ws;

    // ws layout (bytes)
    unsigned short* fvb     = (unsigned short*)(ws);              // 64 MB bf16 fv
    unsigned short* and_W1T = (unsigned short*)(ws + 67108864);   // 1 MB
    unsigned short* or_W1T  = (unsigned short*)(ws + 68157440);   // 1 MB
    unsigned short* and_W2T = (unsigned short*)(ws + 69206016);   // 0.5 MB
    unsigned short* or_W2T  = (unsigned short*)(ws + 69730304);   // 0.5 MB
    unsigned short* not_WT  = (unsigned short*)(ws + 70254592);   // 0.5 MB
    int*            tbl     = (int*)(ws + 70778880);              // 256 B

    SetupArgs sa;
    sa.and_pairs = and_pairs; sa.or_pairs = or_pairs;
    sa.not_idx = not_idx; sa.lidx = leftover; sa.tbl = tbl;
    sa.W[0] = and_W1; sa.WT[0] = and_W1T; sa.K[0] = 1024; sa.N[0] = 512;
    sa.W[1] = or_W1;  sa.WT[1] = or_W1T;  sa.K[1] = 1024; sa.N[1] = 512;
    sa.W[2] = and_W2; sa.WT[2] = and_W2T; sa.K[2] = 512;  sa.N[2] = 512;
    sa.W[3] = or_W2;  sa.WT[3] = or_W2T;  sa.K[3] = 512;  sa.N[3] = 512;
    sa.W[4] = not_W;  sa.WT[4] = not_WT;  sa.K[4] = 512;  sa.N[4] = 512;
    sa.tstart[0] = 0;   sa.tstart[1] = 128; sa.tstart[2] = 256;
    sa.tstart[3] = 320; sa.tstart[4] = 384; sa.tstart[5] = 448;
    setup_kernel<<<dim3(449), dim3(256), 0, stream>>>(sa);

    PrepArgs pa;
    pa.fv = fv; pa.fvb = fvb; pa.tbl = tbl; pa.out = out;
    prep_kernel<<<dim3(16384), dim3(256), 0, stream>>>(pa);

    FArgs fa;
    fa.fvb = fvb;
    fa.and_W1T = and_W1T; fa.and_W2T = and_W2T;
    fa.or_W1T = or_W1T;   fa.or_W2T = or_W2T;   fa.not_WT = not_WT;
    fa.and_pairs = and_pairs; fa.or_pairs = or_pairs; fa.not_idx = not_idx;
    fa.leftover = leftover;
    fa.and_b1 = and_b1; fa.and_b2 = and_b2;
    fa.or_b1 = or_b1;   fa.or_b2 = or_b2;   fa.not_b = not_b;
    fa.out = out;
    fused_phase<<<dim3(512), dim3(256), 0, stream>>>(fa);
}